// Round 1
// baseline (445.258 us; speedup 1.0000x reference)
//
#include <hip/hip_runtime.h>
#include <math.h>

#define DIM 1024
#define NEXP 64
#define TOPK 8
#define BM 64              // tokens per block
#define BK 64              // k-chunk staged in LDS
#define NCHUNK (DIM / BK)  // 16
#define THREADS 256

__global__ __launch_bounds__(THREADS, 2)
void router_topk_kernel(const float* __restrict__ x,
                        const float* __restrict__ W,
                        const float* __restrict__ b,
                        float* __restrict__ out_probs,
                        float* __restrict__ out_idx)
{
    // x_s pad +4 floats (stride 68) -> b128 reads land on distinct bank groups
    __shared__ float x_s[BM][BK + 4];
    // logits pad +1 (stride 65, odd) -> per-lane row access conflict-free
    __shared__ float logits_s[BM][NEXP + 1];

    const int tid  = threadIdx.x;
    const int lane = tid & 63;                                   // token within block
    const int wid  = __builtin_amdgcn_readfirstlane(tid >> 6);   // wave id, SGPR
    const int eb   = wid * 16;                                   // expert base (uniform)
    const int tok0 = blockIdx.x * BM;

    const float* Wb = W + (size_t)eb * DIM;   // uniform pointer -> s_load path

    float acc[16];
#pragma unroll
    for (int j = 0; j < 16; ++j) acc[j] = 0.f;

    // ---- staging helpers: 64 rows x 16 float4 = 1024 float4, 4 per thread ----
    auto prefetch = [&](float4 (&st)[4], int kc) {
        const float* src = x + (size_t)tok0 * DIM + kc * BK;
#pragma unroll
        for (int i = 0; i < 4; ++i) {
            int v = tid + i * THREADS;
            int row = v >> 4, c4 = v & 15;
            st[i] = *(const float4*)(src + (size_t)row * DIM + c4 * 4);
        }
    };
    auto stage_write = [&](float4 (&st)[4]) {
#pragma unroll
        for (int i = 0; i < 4; ++i) {
            int v = tid + i * THREADS;
            int row = v >> 4, c4 = v & 15;
            *(float4*)&x_s[row][c4 * 4] = st[i];
        }
    };
    auto compute = [&](int kc) {
        const float* wp = Wb + kc * BK;
#pragma unroll
        for (int k4 = 0; k4 < BK / 4; ++k4) {
            float4 xv = *(const float4*)&x_s[lane][k4 * 4];
#pragma unroll
            for (int j = 0; j < 16; ++j) {
                // wave-uniform address -> s_load_dwordx4; v_fma with SGPR operand
                float4 wv = *(const float4*)(wp + (size_t)j * DIM + k4 * 4);
                acc[j] = fmaf(xv.x, wv.x, acc[j]);
                acc[j] = fmaf(xv.y, wv.y, acc[j]);
                acc[j] = fmaf(xv.z, wv.z, acc[j]);
                acc[j] = fmaf(xv.w, wv.w, acc[j]);
            }
        }
    };

    // ---- K loop with reg-prefetch ping-pong ----
    float4 stA[4], stB[4];
    prefetch(stA, 0);
    for (int kc = 0; kc < NCHUNK; kc += 2) {
        __syncthreads();                 // previous compute done reading x_s
        stage_write(stA);
        if (kc + 1 < NCHUNK) prefetch(stB, kc + 1);  // latency hidden under compute
        __syncthreads();
        compute(kc);

        __syncthreads();
        stage_write(stB);
        if (kc + 2 < NCHUNK) prefetch(stA, kc + 2);
        __syncthreads();
        compute(kc + 1);
    }

    // ---- epilogue: logits -> LDS (conflict-free: bank = (lane + e) % 32) ----
#pragma unroll
    for (int j = 0; j < 16; ++j)
        logits_s[lane][eb + j] = acc[j] + b[eb + j];
    __syncthreads();

    if (tid < BM) {
        const int t = tid;
        float pv[TOPK]; int pi[TOPK];
#pragma unroll
        for (int k = 0; k < TOPK; ++k) {
            float vmax = -INFINITY; int imax = 0;
#pragma unroll
            for (int e = 0; e < NEXP; ++e) {
                float v = logits_s[t][e];
                if (v > vmax) { vmax = v; imax = e; }   // strict > == JAX tie-break (lowest idx)
            }
            pv[k] = vmax; pi[k] = imax;
            logits_s[t][imax] = -INFINITY;              // mask and rescan
        }

        // softmax over the 8 kept logits (pv[0] is the max)
        float p[TOPK]; float s = 0.f;
#pragma unroll
        for (int k = 0; k < TOPK; ++k) { p[k] = __expf(pv[k] - pv[0]); s += p[k]; }
        float inv = 1.f / s;
#pragma unroll
        for (int k = 0; k < TOPK; ++k) p[k] *= inv;

        // compose sparse prob row in registers, store as 16 float4
        float* orow = out_probs + (size_t)(tok0 + t) * NEXP;
#pragma unroll
        for (int g = 0; g < 16; ++g) {
            float4 z = make_float4(0.f, 0.f, 0.f, 0.f);
#pragma unroll
            for (int k = 0; k < TOPK; ++k) {
                z.x = (pi[k] == g * 4 + 0) ? p[k] : z.x;
                z.y = (pi[k] == g * 4 + 1) ? p[k] : z.y;
                z.z = (pi[k] == g * 4 + 2) ? p[k] : z.z;
                z.w = (pi[k] == g * 4 + 3) ? p[k] : z.w;
            }
            *(float4*)(orow + g * 4) = z;
        }

        // indices written as float values (harness reads d_out as one f32 stream)
        float* irow = out_idx + (size_t)(tok0 + t) * TOPK;
#pragma unroll
        for (int k = 0; k < TOPK; ++k) irow[k] = (float)pi[k];
    }
}

extern "C" void kernel_launch(void* const* d_in, const int* in_sizes, int n_in,
                              void* d_out, int out_size, void* d_ws, size_t ws_size,
                              hipStream_t stream) {
    const float* x = (const float*)d_in[0];
    const float* W = (const float*)d_in[1];
    const float* b = (const float*)d_in[2];
    float* out = (float*)d_out;

    const int ntok = in_sizes[0] / DIM;          // 8*4096 = 32768
    float* out_probs = out;                       // [ntok, 64]
    float* out_idx   = out + (size_t)ntok * NEXP; // [ntok, 8] as float values

    const int grid = ntok / BM;                   // 512 blocks
    router_topk_kernel<<<grid, THREADS, 0, stream>>>(x, W, b, out_probs, out_idx);
}

// Round 2
// 287.382 us; speedup vs baseline: 1.5494x; 1.5494x over previous
//
#include <hip/hip_runtime.h>
#include <math.h>

#define DIM 1024
#define NEXP 64
#define TOPK 8
#define BM 64              // tokens per block
#define BK 64              // k-chunk staged in LDS
#define NCHUNK (DIM / BK)  // 16
#define THREADS 256
#define XPAD 68            // row stride for staged tiles (16B-aligned, conflict-spread)
#define LPAD 65            // logits row stride

__global__ __launch_bounds__(THREADS, 2)
void router_topk_kernel(const float* __restrict__ x,
                        const float* __restrict__ W,
                        const float* __restrict__ b,
                        float* __restrict__ out_probs,
                        float* __restrict__ out_idx)
{
    __shared__ float x_s[BM][XPAD];
    __shared__ float w_s[NEXP][XPAD];
    __shared__ float logits_s[BM][LPAD];   // later reused as prob rows
    __shared__ float topk_s[BM][TOPK];     // selected indices as floats

    const int tid  = threadIdx.x;
    const int trow = tid >> 4;   // 0..15 : token group (token = trow + 16*t)
    const int tcol = tid & 15;   // 0..15 : expert group (expert = tcol + 16*e)
    const int tok0 = blockIdx.x * BM;

    // bias for this thread's 4 experts (issued once, L2-resident)
    float bb[4];
#pragma unroll
    for (int e = 0; e < 4; ++e) bb[e] = b[tcol + 16 * e];

    float acc[4][4];
#pragma unroll
    for (int t = 0; t < 4; ++t)
#pragma unroll
        for (int e = 0; e < 4; ++e) acc[t][e] = 0.f;

    // ---- staging: per chunk, x: 64x64 floats (1024 float4), W: same ----
    auto prefetch = [&](float4 (&px)[4], float4 (&pw)[4], int kc) {
        const float* xsrc = x + (size_t)tok0 * DIM + (size_t)kc * BK;
        const float* wsrc = W + (size_t)kc * BK;
#pragma unroll
        for (int i = 0; i < 4; ++i) {
            int v = tid + i * THREADS;
            int row = v >> 4, c4 = v & 15;
            px[i] = *(const float4*)(xsrc + (size_t)row * DIM + c4 * 4);
            pw[i] = *(const float4*)(wsrc + (size_t)row * DIM + c4 * 4);
        }
    };
    auto stage = [&](float4 (&px)[4], float4 (&pw)[4]) {
#pragma unroll
        for (int i = 0; i < 4; ++i) {
            int v = tid + i * THREADS;
            int row = v >> 4, c4 = v & 15;
            *(float4*)&x_s[row][c4 * 4] = px[i];
            *(float4*)&w_s[row][c4 * 4] = pw[i];
        }
    };
    auto compute = [&]() {
#pragma unroll
        for (int k4 = 0; k4 < BK / 4; ++k4) {
            float4 xa[4], wa[4];
#pragma unroll
            for (int t = 0; t < 4; ++t)
                xa[t] = *(const float4*)&x_s[trow + 16 * t][k4 * 4];
#pragma unroll
            for (int e = 0; e < 4; ++e)
                wa[e] = *(const float4*)&w_s[tcol + 16 * e][k4 * 4];
#pragma unroll
            for (int t = 0; t < 4; ++t)
#pragma unroll
                for (int e = 0; e < 4; ++e) {
                    acc[t][e] = fmaf(xa[t].x, wa[e].x, acc[t][e]);
                    acc[t][e] = fmaf(xa[t].y, wa[e].y, acc[t][e]);
                    acc[t][e] = fmaf(xa[t].z, wa[e].z, acc[t][e]);
                    acc[t][e] = fmaf(xa[t].w, wa[e].w, acc[t][e]);
                }
        }
    };

    // ---- main K loop: reg-prefetch next chunk, compute current from LDS ----
    float4 px[4], pw[4];
    prefetch(px, pw, 0);
    for (int kc = 0; kc < NCHUNK; ++kc) {
        __syncthreads();              // previous compute done reading LDS
        stage(px, pw);                // vmcnt wait lands here
        __syncthreads();
        if (kc + 1 < NCHUNK) prefetch(px, pw, kc + 1);  // hidden under compute
        compute();
    }

    // ---- logits (+bias) to LDS ----
    __syncthreads();
#pragma unroll
    for (int t = 0; t < 4; ++t)
#pragma unroll
        for (int e = 0; e < 4; ++e)
            logits_s[trow + 16 * t][tcol + 16 * e] = acc[t][e] + bb[e];
    __syncthreads();

    // ---- top-8 scan + softmax, one lane per token (wave 0) ----
    if (tid < BM) {
        const int t = tid;
        float pv[TOPK]; int pi[TOPK];
#pragma unroll
        for (int k = 0; k < TOPK; ++k) {
            float vmax = -INFINITY; int imax = 0;
#pragma unroll
            for (int e = 0; e < NEXP; ++e) {
                float v = logits_s[t][e];
                if (v > vmax) { vmax = v; imax = e; }   // strict > == lowest-index tie-break
            }
            pv[k] = vmax; pi[k] = imax;
            logits_s[t][imax] = -INFINITY;
        }
        float p[TOPK]; float s = 0.f;
#pragma unroll
        for (int k = 0; k < TOPK; ++k) { p[k] = __expf(pv[k] - pv[0]); s += p[k]; }
        float inv = 1.f / s;

        // overwrite logits row with sparse prob row (zeros + 8 probs)
#pragma unroll
        for (int e = 0; e < NEXP; ++e) logits_s[t][e] = 0.f;
#pragma unroll
        for (int k = 0; k < TOPK; ++k) {
            logits_s[t][pi[k]] = p[k] * inv;
            topk_s[t][k] = (float)pi[k];
        }
    }
    __syncthreads();

    // ---- coalesced output copy: probs 64x64 = 1024 float4, 4/thread ----
#pragma unroll
    for (int i = 0; i < 4; ++i) {
        int v = tid + i * THREADS;
        int row = v >> 4, c = (v & 15) * 4;
        float4 z = make_float4(logits_s[row][c], logits_s[row][c + 1],
                               logits_s[row][c + 2], logits_s[row][c + 3]);
        *(float4*)(out_probs + (size_t)(tok0 + row) * NEXP + c) = z;
    }
    // indices: 64x8 floats = 128 float4, threads 0..127
    if (tid < 128) {
        int row = tid >> 1, c4 = tid & 1;
        float4 z = *(const float4*)&topk_s[row][c4 * 4];
        *(float4*)(out_idx + (size_t)(tok0 + row) * TOPK + c4 * 4) = z;
    }
}

extern "C" void kernel_launch(void* const* d_in, const int* in_sizes, int n_in,
                              void* d_out, int out_size, void* d_ws, size_t ws_size,
                              hipStream_t stream) {
    const float* x = (const float*)d_in[0];
    const float* W = (const float*)d_in[1];
    const float* b = (const float*)d_in[2];
    float* out = (float*)d_out;

    const int ntok = in_sizes[0] / DIM;           // 32768
    float* out_probs = out;                        // [ntok, 64]
    float* out_idx   = out + (size_t)ntok * NEXP;  // [ntok, 8] as float values

    const int grid = ntok / BM;                    // 512 blocks
    router_topk_kernel<<<grid, THREADS, 0, stream>>>(x, W, b, out_probs, out_idx);
}